// Round 3
// baseline (561.998 us; speedup 1.0000x reference)
//
#include <hip/hip_runtime.h>

typedef __attribute__((ext_vector_type(8))) __bf16 bf16x8;
typedef __attribute__((ext_vector_type(4))) __bf16 bf16x4;
typedef __attribute__((ext_vector_type(4))) float f32x4;

#define MFMA16(a,b,c) __builtin_amdgcn_mfma_f32_16x16x32_bf16(a,b,c,0,0,0)
#define QSCALE 0.17677669529663687f  // 1/sqrt(32)

// ---------------- workspace layout (bytes) ----------------
// wqkv : __bf16[110592] @ 0        [h][ctl0..5][ks0..5][lane][j]  (221184 B)
//        ctl: 0,1=q cols h*32+{0..15,16..31}; 2,3=k; 4,5=v
// wproj: __bf16[36864]  @ 221184   [ct0..11][ks0..5][lane][j]     (73728 B)
// biasf: float [24576]  @ 294912   [h][mt][nt][lane][r]           (98304 B)
// maskf: float [262144] @ 393216   [w][mt][nt][lane][r]           (1048576 B)
#define NWQKV  110592
#define NWPROJ 36864
#define NBIAS  24576
#define NMASK  262144

__global__ void prep_kernel(const float* __restrict__ qkv_w,
                            const float* __restrict__ proj_w,
                            const float* __restrict__ bias_table,
                            const int*   __restrict__ rel_index,
                            const float* __restrict__ mask,
                            __bf16* __restrict__ wqkv,
                            __bf16* __restrict__ wproj,
                            float* __restrict__ biasf,
                            float* __restrict__ maskf)
{
    int idx = blockIdx.x * 256 + threadIdx.x;
    if (idx < NWQKV) {
        int h   = idx / 18432; int rem = idx - h * 18432;
        int ctl = rem / 3072;  int rem2 = rem - ctl * 3072;
        int ks  = rem2 >> 9; int lane = (rem2 >> 3) & 63; int j = rem2 & 7;
        int sec = ctl >> 1;
        int o   = sec * 192 + h * 32 + (ctl & 1) * 16 + (lane & 15);
        int kk  = ks * 32 + (lane >> 4) * 8 + j;
        wqkv[idx] = (__bf16)qkv_w[o * 192 + kk];
        return;
    }
    idx -= NWQKV;
    if (idx < NWPROJ) {
        int ct = idx / 3072; int rem = idx - ct * 3072;
        int ks = rem >> 9; int lane = (rem >> 3) & 63; int j = rem & 7;
        int o  = ct * 16 + (lane & 15);
        int kk = ks * 32 + (lane >> 4) * 8 + j;
        wproj[idx] = (__bf16)proj_w[o * 192 + kk];
        return;
    }
    idx -= NWPROJ;
    if (idx < NBIAS) {
        int h = idx >> 12; int rem = idx & 4095;
        int mt = (rem >> 10) & 3, nt = (rem >> 8) & 3;
        int lane = (rem >> 2) & 63, r = rem & 3;
        int m  = mt * 16 + (lane >> 4) * 4 + r;   // query row
        int nn = nt * 16 + (lane & 15);           // key col
        float v;
        if (nn >= 49)      v = -1e30f;            // kill padded key cols
        else if (m >= 49)  v = 0.f;
        else               v = bias_table[rel_index[m * 49 + nn] * 6 + h];
        biasf[idx] = v;
        return;
    }
    idx -= NBIAS;
    if (idx < NMASK) {
        int w = idx >> 12; int rem = idx & 4095;
        int mt = (rem >> 10) & 3, nt = (rem >> 8) & 3;
        int lane = (rem >> 2) & 63, r = rem & 3;
        int m  = mt * 16 + (lane >> 4) * 4 + r;
        int nn = nt * 16 + (lane & 15);
        maskf[idx] = (m < 49 && nn < 49) ? mask[(w * 49 + m) * 49 + nn] : 0.f;
    }
}

// One block = one window. 384 threads = 6 waves; wave wv owns head wv.
// LDS (72 KB -> 2 blocks/CU):
//   s_x  [12288 bf16] : x as [cb 24][tok 64][8]  (24 KB, shared)
//   s_scr[6][4096 bf16]: per-wave scratch. A=[0,2048): q -> k -> P-halves ->
//   attn_out, all as [sub 4][tok 64][8]. B=[2048,4096): vT as [tt 8][d 32][8].
__global__ __launch_bounds__(384, 3)
void win_attn_kernel(const float* __restrict__ x,
                     const float* __restrict__ qkv_b,
                     const float* __restrict__ proj_b,
                     const __bf16* __restrict__ wqkv,
                     const __bf16* __restrict__ wproj,
                     const float* __restrict__ biasf,
                     const float* __restrict__ maskf,
                     float* __restrict__ out)
{
    __shared__ __bf16 s_x[12288];
    __shared__ __bf16 s_scr[24576];

    const int b    = blockIdx.x;
    const int tid  = threadIdx.x;
    const int wv   = tid >> 6;
    const int lane = tid & 63;
    const int g    = lane >> 4;
    const int ln   = lane & 15;
    const f32x4 fzero = {0.f, 0.f, 0.f, 0.f};

    // ---------------- phase 0: stage x -> bf16 LDS (coalesced float4) -------
    {
        const float* xg = x + (size_t)b * 9408;
        #pragma unroll
        for (int it = 0; it < 7; ++it) {
            int idx = it * 384 + tid;
            if (idx < 2352) {                       // 49 rows * 48 float4
                int row = idx / 48, c4 = idx - row * 48, c0 = c4 * 4;
                const float4 f = *reinterpret_cast<const float4*>(xg + row * 192 + c0);
                bf16x4 h;
                h[0] = (__bf16)f.x; h[1] = (__bf16)f.y;
                h[2] = (__bf16)f.z; h[3] = (__bf16)f.w;
                *reinterpret_cast<bf16x4*>(&s_x[((c0 >> 3) * 64 + row) * 8 + (c0 & 7)]) = h;
            }
        }
        if (tid < 360) {                            // zero rows 49..63
            int row = 49 + tid / 24, cb = tid - (tid / 24) * 24;
            bf16x8 z = {};
            *reinterpret_cast<bf16x8*>(&s_x[(cb * 64 + row) * 8]) = z;
        }
    }
    __syncthreads();

    __bf16* A = &s_scr[wv * 4096];
    __bf16* B = A + 2048;
    float rinv[4][4];

    // ---------------- phase 1+2: per-wave, barrier-free ----------------
    {
        // qkv projection for own head: 6 col-tiles (q0 q1 k0 k1 v0 v1)
        f32x4 acc[6][4];
        #pragma unroll
        for (int c = 0; c < 6; ++c)
            #pragma unroll
            for (int mt = 0; mt < 4; ++mt) acc[c][mt] = fzero;

        const __bf16* wq = wqkv + (size_t)wv * 18432;
        #pragma unroll
        for (int ks = 0; ks < 6; ++ks) {
            bf16x8 a[4], bb[6];
            #pragma unroll
            for (int mt = 0; mt < 4; ++mt)
                a[mt] = *reinterpret_cast<const bf16x8*>(
                    &s_x[((ks * 4 + g) * 64 + mt * 16 + ln) * 8]);
            #pragma unroll
            for (int c = 0; c < 6; ++c)
                bb[c] = *reinterpret_cast<const bf16x8*>(&wq[(c * 6 + ks) * 512 + lane * 8]);
            #pragma unroll
            for (int c = 0; c < 6; ++c)
                #pragma unroll
                for (int mt = 0; mt < 4; ++mt)
                    acc[c][mt] = MFMA16(a[mt], bb[c], acc[c][mt]);
        }

        // v -> B region, vT layout [tok>>3][d][tok&7] (b64-packed in r)
        #pragma unroll
        for (int c2 = 0; c2 < 2; ++c2) {
            int c = c2 * 16 + ln;
            float bo = qkv_b[384 + wv * 32 + c];
            #pragma unroll
            for (int mt = 0; mt < 4; ++mt) {
                int m0 = mt * 16 + g * 4;
                bf16x4 h;
                #pragma unroll
                for (int r = 0; r < 4; ++r) h[r] = (__bf16)(acc[4 + c2][mt][r] + bo);
                *reinterpret_cast<bf16x4*>(&B[((m0 >> 3) * 32 + c) * 8 + (m0 & 7)]) = h;
            }
        }
        // q -> A region [d>>3][tok][d&7], scaled
        #pragma unroll
        for (int c2 = 0; c2 < 2; ++c2) {
            int c = c2 * 16 + ln;
            float bo = qkv_b[wv * 32 + c];
            #pragma unroll
            for (int mt = 0; mt < 4; ++mt)
                #pragma unroll
                for (int r = 0; r < 4; ++r) {
                    int m = mt * 16 + g * 4 + r;
                    A[((c >> 3) * 64 + m) * 8 + (c & 7)] = (__bf16)((acc[c2][mt][r] + bo) * QSCALE);
                }
        }
        bf16x8 qa[4];
        #pragma unroll
        for (int mt = 0; mt < 4; ++mt)
            qa[mt] = *reinterpret_cast<const bf16x8*>(&A[(g * 64 + mt * 16 + ln) * 8]);

        // k -> A region (overwrites q; in-order DS makes WAR safe)
        #pragma unroll
        for (int c2 = 0; c2 < 2; ++c2) {
            int c = c2 * 16 + ln;
            float bo = qkv_b[192 + wv * 32 + c];
            #pragma unroll
            for (int mt = 0; mt < 4; ++mt)
                #pragma unroll
                for (int r = 0; r < 4; ++r) {
                    int m = mt * 16 + g * 4 + r;
                    A[((c >> 3) * 64 + m) * 8 + (c & 7)] = (__bf16)(acc[2 + c2][mt][r] + bo);
                }
        }
        bf16x8 ka[4];
        #pragma unroll
        for (int nt = 0; nt < 4; ++nt)
            ka[nt] = *reinterpret_cast<const bf16x8*>(&A[(g * 64 + nt * 16 + ln) * 8]);

        // S = q k^T + (bias+mask) via MFMA C-operand
        const float* bf_ = biasf + wv * 4096;
        const float* mf_ = maskf + (b & 63) * 4096;
        f32x4 S[4][4];
        #pragma unroll
        for (int mt = 0; mt < 4; ++mt)
            #pragma unroll
            for (int nt = 0; nt < 4; ++nt) {
                f32x4 bv = *reinterpret_cast<const f32x4*>(&bf_[((mt * 4 + nt) * 64 + lane) * 4]);
                f32x4 mv = *reinterpret_cast<const f32x4*>(&mf_[((mt * 4 + nt) * 64 + lane) * 4]);
                f32x4 cc;
                #pragma unroll
                for (int r = 0; r < 4; ++r) cc[r] = bv[r] + mv[r];
                S[mt][nt] = MFMA16(qa[mt], ka[nt], cc);
            }

        // softmax, no max-sub (logits O(+-6); padded cols are -1e30 -> exp=0)
        #pragma unroll
        for (int mt = 0; mt < 4; ++mt)
            #pragma unroll
            for (int r = 0; r < 4; ++r) {
                float e0 = __expf(S[mt][0][r]);
                float e1 = __expf(S[mt][1][r]);
                float e2 = __expf(S[mt][2][r]);
                float e3 = __expf(S[mt][3][r]);
                S[mt][0][r] = e0; S[mt][1][r] = e1;
                S[mt][2][r] = e2; S[mt][3][r] = e3;
                float sum = (e0 + e1) + (e2 + e3);
                sum += __shfl_xor(sum, 1, 64);
                sum += __shfl_xor(sum, 2, 64);
                sum += __shfl_xor(sum, 4, 64);
                sum += __shfl_xor(sum, 8, 64);
                rinv[mt][r] = __builtin_amdgcn_rcpf(sum);
            }

        // PV in two K=32 halves; P half staged through A (k dead)
        f32x4 oacc[4][2];
        #pragma unroll
        for (int mt = 0; mt < 4; ++mt) { oacc[mt][0] = fzero; oacc[mt][1] = fzero; }
        #pragma unroll
        for (int half = 0; half < 2; ++half) {
            #pragma unroll
            for (int mt = 0; mt < 4; ++mt)
                #pragma unroll
                for (int nt2 = 0; nt2 < 2; ++nt2) {
                    int nt = half * 2 + nt2;
                    int kt = nt2 * 16 + ln;
                    #pragma unroll
                    for (int r = 0; r < 4; ++r) {
                        int m = mt * 16 + g * 4 + r;
                        A[((kt >> 3) * 64 + m) * 8 + (kt & 7)] = (__bf16)S[mt][nt][r];
                    }
                }
            bf16x8 vf[2];
            #pragma unroll
            for (int nt2 = 0; nt2 < 2; ++nt2)
                vf[nt2] = *reinterpret_cast<const bf16x8*>(
                    &B[((half * 4 + g) * 32 + nt2 * 16 + ln) * 8]);
            #pragma unroll
            for (int mt = 0; mt < 4; ++mt) {
                bf16x8 pa = *reinterpret_cast<const bf16x8*>(
                    &A[(g * 64 + mt * 16 + ln) * 8]);
                #pragma unroll
                for (int nt2 = 0; nt2 < 2; ++nt2)
                    oacc[mt][nt2] = MFMA16(pa, vf[nt2], oacc[mt][nt2]);
            }
        }

        // normalized attn_out -> A region [d>>3][tok][d&7]
        #pragma unroll
        for (int mt = 0; mt < 4; ++mt)
            #pragma unroll
            for (int nt2 = 0; nt2 < 2; ++nt2)
                #pragma unroll
                for (int r = 0; r < 4; ++r) {
                    int m = mt * 16 + g * 4 + r;
                    int d = nt2 * 16 + ln;
                    A[((d >> 3) * 64 + m) * 8 + (d & 7)] =
                        (__bf16)(oacc[mt][nt2][r] * rinv[mt][r]);
                }
    }
    __syncthreads();

    // ---------------- phase 3: output projection ----------------
    {
        f32x4 acc[2][4];
        #pragma unroll
        for (int i = 0; i < 2; ++i)
            #pragma unroll
            for (int mt = 0; mt < 4; ++mt) acc[i][mt] = fzero;

        #pragma unroll
        for (int ks = 0; ks < 6; ++ks) {
            bf16x8 a[4], bb[2];
            #pragma unroll
            for (int mt = 0; mt < 4; ++mt)
                a[mt] = *reinterpret_cast<const bf16x8*>(
                    &s_scr[ks * 4096 + (g * 64 + mt * 16 + ln) * 8]);
            #pragma unroll
            for (int i = 0; i < 2; ++i)
                bb[i] = *reinterpret_cast<const bf16x8*>(
                    &wproj[((wv * 2 + i) * 6 + ks) * 512 + lane * 8]);
            #pragma unroll
            for (int i = 0; i < 2; ++i)
                #pragma unroll
                for (int mt = 0; mt < 4; ++mt)
                    acc[i][mt] = MFMA16(a[mt], bb[i], acc[i][mt]);
        }
        #pragma unroll
        for (int i = 0; i < 2; ++i) {
            int o = (wv * 2 + i) * 16 + ln;
            float pbv = proj_b[o];
            #pragma unroll
            for (int mt = 0; mt < 4; ++mt)
                #pragma unroll
                for (int r = 0; r < 4; ++r) {
                    int m = mt * 16 + g * 4 + r;
                    if (m < 49)
                        out[((size_t)b * 49 + m) * 192 + o] = acc[i][mt][r] + pbv;
                }
        }
    }
}

extern "C" void kernel_launch(void* const* d_in, const int* in_sizes, int n_in,
                              void* d_out, int out_size, void* d_ws, size_t ws_size,
                              hipStream_t stream) {
    const float* x        = (const float*)d_in[0];
    const float* mask     = (const float*)d_in[1];
    const float* qkv_w    = (const float*)d_in[2];
    const float* qkv_b    = (const float*)d_in[3];
    const float* proj_w   = (const float*)d_in[4];
    const float* proj_b   = (const float*)d_in[5];
    const float* bias_tab = (const float*)d_in[6];
    const int*   rel_idx  = (const int*)d_in[7];

    __bf16* wqkv  = (__bf16*)d_ws;
    __bf16* wproj = wqkv + NWQKV;
    float*  biasf = (float*)((char*)d_ws + 294912);
    float*  maskf = (float*)((char*)d_ws + 393216);

    const int total = NWQKV + NWPROJ + NBIAS + NMASK;   // 434176
    prep_kernel<<<(total + 255) / 256, 256, 0, stream>>>(
        qkv_w, proj_w, bias_tab, rel_idx, mask, wqkv, wproj, biasf, maskf);

    win_attn_kernel<<<4096, 384, 0, stream>>>(
        x, qkv_b, proj_b, wqkv, wproj, biasf, maskf, (float*)d_out);
}

// Round 9
// 436.022 us; speedup vs baseline: 1.2889x; 1.2889x over previous
//
#include <hip/hip_runtime.h>

typedef __attribute__((ext_vector_type(8))) __bf16 bf16x8;
typedef __attribute__((ext_vector_type(4))) __bf16 bf16x4;
typedef __attribute__((ext_vector_type(4))) float f32x4;

#define MFMA16(a,b,c) __builtin_amdgcn_mfma_f32_16x16x32_bf16(a,b,c,0,0,0)
#define QSCALE 0.17677669529663687f  // 1/sqrt(32)

// ---------------- workspace layout (bytes) ----------------
// wqkv : __bf16[110592] @ 0        [h][ctl0..5][ks0..5][lane][j]  (221184 B)
//        ctl: 0,1=q cols h*32+{0..15,16..31}; 2,3=k; 4,5=v
// wproj: __bf16[36864]  @ 221184   [ct0..11][ks0..5][lane][j]     (73728 B)
// biasf: float [24576]  @ 294912   [h][ntK][mtQ][lane][r]  (S^T frag order)
// maskf: float [262144] @ 393216   [w][ntK][mtQ][lane][r]
#define NWQKV  110592
#define NWPROJ 36864
#define NBIAS  24576
#define NMASK  262144

__global__ void prep_kernel(const float* __restrict__ qkv_w,
                            const float* __restrict__ proj_w,
                            const float* __restrict__ bias_table,
                            const int*   __restrict__ rel_index,
                            const float* __restrict__ mask,
                            __bf16* __restrict__ wqkv,
                            __bf16* __restrict__ wproj,
                            float* __restrict__ biasf,
                            float* __restrict__ maskf)
{
    int idx = blockIdx.x * 256 + threadIdx.x;
    if (idx < NWQKV) {
        int h   = idx / 18432; int rem = idx - h * 18432;
        int ctl = rem / 3072;  int rem2 = rem - ctl * 3072;
        int ks  = rem2 >> 9; int lane = (rem2 >> 3) & 63; int j = rem2 & 7;
        int sec = ctl >> 1;
        int o   = sec * 192 + h * 32 + (ctl & 1) * 16 + (lane & 15);
        int kk  = ks * 32 + (lane >> 4) * 8 + j;
        wqkv[idx] = (__bf16)qkv_w[o * 192 + kk];
        return;
    }
    idx -= NWQKV;
    if (idx < NWPROJ) {
        int ct = idx / 3072; int rem = idx - ct * 3072;
        int ks = rem >> 9; int lane = (rem >> 3) & 63; int j = rem & 7;
        int o  = ct * 16 + (lane & 15);
        int kk = ks * 32 + (lane >> 4) * 8 + j;
        wproj[idx] = (__bf16)proj_w[o * 192 + kk];
        return;
    }
    idx -= NWPROJ;
    if (idx < NBIAS) {      // S^T fragment order: col=query, row=key
        int h = idx >> 12; int rem = idx & 4095;
        int nt = (rem >> 10) & 3, mt = (rem >> 8) & 3;
        int lane = (rem >> 2) & 63, r = rem & 3;
        int m  = mt * 16 + (lane & 15);           // query col
        int nn = nt * 16 + (lane >> 4) * 4 + r;   // key row
        float v;
        if (nn >= 49)      v = -1e30f;            // kill padded key rows
        else if (m >= 49)  v = 0.f;
        else               v = bias_table[rel_index[m * 49 + nn] * 6 + h];
        biasf[idx] = v;
        return;
    }
    idx -= NBIAS;
    if (idx < NMASK) {
        int w = idx >> 12; int rem = idx & 4095;
        int nt = (rem >> 10) & 3, mt = (rem >> 8) & 3;
        int lane = (rem >> 2) & 63, r = rem & 3;
        int m  = mt * 16 + (lane & 15);
        int nn = nt * 16 + (lane >> 4) * 4 + r;
        maskf[idx] = (m < 49 && nn < 49) ? mask[(w * 49 + m) * 49 + nn] : 0.f;
    }
}

// One block = one window, 384 thr = 6 waves; wave wv owns head wv.
// LDS 75264 B:
//  s_x [12480] : x bf16, [cb 24][row 64][8], cb-stride 520 (pad kills conflicts)
//  s_v [12672] : per wave 2112: vT [tt 8][d 32][8], tt-stride 264
//  s_a [12480] : per wave 2080: [sub 4][idx 64][8], sub-stride 520
//                q -> k -> P^T halves -> attn_out (time-shared)
__global__ __launch_bounds__(384, 4)
void win_attn_kernel(const float* __restrict__ x,
                     const float* __restrict__ qkv_b,
                     const float* __restrict__ proj_b,
                     const __bf16* __restrict__ wqkv,
                     const __bf16* __restrict__ wproj,
                     const float* __restrict__ biasf,
                     const float* __restrict__ maskf,
                     float* __restrict__ out)
{
    __shared__ __bf16 s_x[12480];
    __shared__ __bf16 s_v[12672];
    __shared__ __bf16 s_a[12480];

    const int b    = blockIdx.x;
    const int tid  = threadIdx.x;
    const int wv   = tid >> 6;
    const int lane = tid & 63;
    const int g    = lane >> 4;
    const int ln   = lane & 15;
    const f32x4 fzero = {0.f, 0.f, 0.f, 0.f};

    // ---------------- phase 0: stage x -> bf16 LDS ----------------
    {
        const float* xg = x + (size_t)b * 9408;
        #pragma unroll
        for (int it = 0; it < 7; ++it) {
            int idx = it * 384 + tid;
            if (idx < 2352) {                        // 49 rows * 48 float4
                int row = idx / 48, c4 = idx - row * 48, c0 = c4 * 4;
                const float4 f = *reinterpret_cast<const float4*>(xg + row * 192 + c0);
                bf16x4 h;
                h[0] = (__bf16)f.x; h[1] = (__bf16)f.y;
                h[2] = (__bf16)f.z; h[3] = (__bf16)f.w;
                *reinterpret_cast<bf16x4*>(&s_x[(c0 >> 3) * 520 + row * 8 + (c0 & 7)]) = h;
            }
        }
        if (tid < 360) {                             // zero rows 49..63
            int q24 = tid / 24;
            int row = 49 + q24, cb = tid - q24 * 24;
            bf16x8 z = {};
            *reinterpret_cast<bf16x8*>(&s_x[cb * 520 + row * 8]) = z;
        }
    }
    __syncthreads();

    __bf16* A = &s_a[wv * 2080];
    __bf16* V = &s_v[wv * 2112];
    const __bf16* wq = wqkv + (size_t)wv * 18432;

    bf16x8 qB[4], ka[4];

    // ---------------- pass A: q,k projection (64-reg acc) ----------------
    {
        f32x4 acc[4][4];                 // [ctl 0..3 = q0 q1 k0 k1][mt]
        #pragma unroll
        for (int c = 0; c < 4; ++c)
            #pragma unroll
            for (int mt = 0; mt < 4; ++mt) acc[c][mt] = fzero;

        #pragma unroll
        for (int ks = 0; ks < 6; ++ks) {
            bf16x8 a[4], bb[4];
            #pragma unroll
            for (int mt = 0; mt < 4; ++mt)
                a[mt] = *reinterpret_cast<const bf16x8*>(
                    &s_x[(ks * 4 + g) * 520 + (mt * 16 + ln) * 8]);
            #pragma unroll
            for (int c = 0; c < 4; ++c)
                bb[c] = *reinterpret_cast<const bf16x8*>(&wq[(c * 6 + ks) * 512 + lane * 8]);
            #pragma unroll
            for (int c = 0; c < 4; ++c)
                #pragma unroll
                for (int mt = 0; mt < 4; ++mt)
                    acc[c][mt] = MFMA16(a[mt], bb[c], acc[c][mt]);
        }

        // q -> A [d>>3][tok][d&7], scaled; then read qB frags
        #pragma unroll
        for (int c2 = 0; c2 < 2; ++c2) {
            int d = c2 * 16 + ln;
            float bo = qkv_b[wv * 32 + c2 * 16 + ln];
            #pragma unroll
            for (int mt = 0; mt < 4; ++mt)
                #pragma unroll
                for (int r = 0; r < 4; ++r)
                    A[(d >> 3) * 520 + (mt * 16 + g * 4 + r) * 8 + (d & 7)] =
                        (__bf16)((acc[c2][mt][r] + bo) * QSCALE);
        }
        #pragma unroll
        for (int mt = 0; mt < 4; ++mt)
            qB[mt] = *reinterpret_cast<const bf16x8*>(&A[g * 520 + (mt * 16 + ln) * 8]);

        // k -> A (overwrites q; in-order DS keeps WAR safe); read ka frags
        #pragma unroll
        for (int c2 = 0; c2 < 2; ++c2) {
            int d = c2 * 16 + ln;
            float bo = qkv_b[192 + wv * 32 + c2 * 16 + ln];
            #pragma unroll
            for (int mt = 0; mt < 4; ++mt)
                #pragma unroll
                for (int r = 0; r < 4; ++r)
                    A[(d >> 3) * 520 + (mt * 16 + g * 4 + r) * 8 + (d & 7)] =
                        (__bf16)(acc[2 + c2][mt][r] + bo);
        }
        #pragma unroll
        for (int nt = 0; nt < 4; ++nt)
            ka[nt] = *reinterpret_cast<const bf16x8*>(&A[g * 520 + (nt * 16 + ln) * 8]);
    }

    // ---------------- pass B: v projection (32-reg acc) ----------------
    {
        f32x4 av[2][4];
        #pragma unroll
        for (int i = 0; i < 2; ++i)
            #pragma unroll
            for (int mt = 0; mt < 4; ++mt) av[i][mt] = fzero;

        #pragma unroll
        for (int ks = 0; ks < 6; ++ks) {
            bf16x8 a[4], bv[2];
            #pragma unroll
            for (int mt = 0; mt < 4; ++mt)
                a[mt] = *reinterpret_cast<const bf16x8*>(
                    &s_x[(ks * 4 + g) * 520 + (mt * 16 + ln) * 8]);
            #pragma unroll
            for (int i = 0; i < 2; ++i)
                bv[i] = *reinterpret_cast<const bf16x8*>(&wq[((4 + i) * 6 + ks) * 512 + lane * 8]);
            #pragma unroll
            for (int i = 0; i < 2; ++i)
                #pragma unroll
                for (int mt = 0; mt < 4; ++mt)
                    av[i][mt] = MFMA16(a[mt], bv[i], av[i][mt]);
        }
        // vT -> V [tok>>3][d][tok&7], b64-packed over r
        #pragma unroll
        for (int c2 = 0; c2 < 2; ++c2) {
            int d = c2 * 16 + ln;
            float bo = qkv_b[384 + wv * 32 + c2 * 16 + ln];
            #pragma unroll
            for (int mt = 0; mt < 4; ++mt) {
                bf16x4 h;
                #pragma unroll
                for (int r = 0; r < 4; ++r) h[r] = (__bf16)(av[c2][mt][r] + bo);
                *reinterpret_cast<bf16x4*>(
                    &V[(2 * mt + (g >> 1)) * 264 + d * 8 + (g & 1) * 4]) = h;
            }
        }
    }

    // ---------------- attention: S^T = K·Q^T, softmax in-lane, O^T = V^T·P^T --
    float rinv[4];
    {
        const float* bf_ = biasf + wv * 4096;
        const float* mf_ = maskf + (b & 63) * 4096;
        f32x4 oT[2][4];
        #pragma unroll
        for (int dt = 0; dt < 2; ++dt)
            #pragma unroll
            for (int mt = 0; mt < 4; ++mt) oT[dt][mt] = fzero;
        float sums[4] = {0.f, 0.f, 0.f, 0.f};

        #pragma unroll
        for (int kh = 0; kh < 2; ++kh) {
            #pragma unroll
            for (int nt2 = 0; nt2 < 2; ++nt2) {
                int nt = kh * 2 + nt2;
                #pragma unroll
                for (int mt = 0; mt < 4; ++mt) {
                    f32x4 bv = *reinterpret_cast<const f32x4*>(&bf_[((nt * 4 + mt) * 64 + lane) * 4]);
                    f32x4 mv = *reinterpret_cast<const f32x4*>(&mf_[((nt * 4 + mt) * 64 + lane) * 4]);
                    f32x4 cc;
                    #pragma unroll
                    for (int r = 0; r < 4; ++r) cc[r] = bv[r] + mv[r];
                    f32x4 S = MFMA16(ka[nt], qB[mt], cc);
                    float e0 = __expf(S[0]), e1 = __expf(S[1]);
                    float e2 = __expf(S[2]), e3 = __expf(S[3]);
                    sums[mt] += (e0 + e1) + (e2 + e3);
                    bf16x4 h;
                    h[0] = (__bf16)e0; h[1] = (__bf16)e1;
                    h[2] = (__bf16)e2; h[3] = (__bf16)e3;
                    // P^T half -> A [keyloc>>3][query][keyloc&7], b64 over r
                    *reinterpret_cast<bf16x4*>(
                        &A[(nt2 * 2 + (g >> 1)) * 520 + (mt * 16 + ln) * 8 + (g & 1) * 4]) = h;
                }
            }
            // PV for this 32-key half
            bf16x8 avf[2], pB[4];
            #pragma unroll
            for (int dt = 0; dt < 2; ++dt)
                avf[dt] = *reinterpret_cast<const bf16x8*>(
                    &V[(kh * 4 + g) * 264 + (dt * 16 + ln) * 8]);
            #pragma unroll
            for (int mt = 0; mt < 4; ++mt)
                pB[mt] = *reinterpret_cast<const bf16x8*>(&A[g * 520 + (mt * 16 + ln) * 8]);
            #pragma unroll
            for (int dt = 0; dt < 2; ++dt)
                #pragma unroll
                for (int mt = 0; mt < 4; ++mt)
                    oT[dt][mt] = MFMA16(avf[dt], pB[mt], oT[dt][mt]);
        }

        #pragma unroll
        for (int mt = 0; mt < 4; ++mt) {
            float s = sums[mt];
            s += __shfl_xor(s, 16, 64);
            s += __shfl_xor(s, 32, 64);
            rinv[mt] = __builtin_amdgcn_rcpf(s);
        }

        // attn_out -> A [d>>3][tok][d&7], b64-packed over r
        #pragma unroll
        for (int dt = 0; dt < 2; ++dt)
            #pragma unroll
            for (int mt = 0; mt < 4; ++mt) {
                bf16x4 h;
                #pragma unroll
                for (int r = 0; r < 4; ++r) h[r] = (__bf16)(oT[dt][mt][r] * rinv[mt]);
                *reinterpret_cast<bf16x4*>(
                    &A[(dt * 2 + (g >> 1)) * 520 + (mt * 16 + ln) * 8 + (g & 1) * 4]) = h;
            }
    }
    __syncthreads();

    // ---------------- phase 3: output projection ----------------
    {
        f32x4 po[2][4];
        #pragma unroll
        for (int i = 0; i < 2; ++i)
            #pragma unroll
            for (int mt = 0; mt < 4; ++mt) po[i][mt] = fzero;

        #pragma unroll
        for (int ks = 0; ks < 6; ++ks) {
            bf16x8 aa[4], bb[2];
            #pragma unroll
            for (int mt = 0; mt < 4; ++mt)
                aa[mt] = *reinterpret_cast<const bf16x8*>(
                    &s_a[ks * 2080 + g * 520 + (mt * 16 + ln) * 8]);
            #pragma unroll
            for (int i = 0; i < 2; ++i)
                bb[i] = *reinterpret_cast<const bf16x8*>(
                    &wproj[((wv * 2 + i) * 6 + ks) * 512 + lane * 8]);
            #pragma unroll
            for (int i = 0; i < 2; ++i)
                #pragma unroll
                for (int mt = 0; mt < 4; ++mt)
                    po[i][mt] = MFMA16(aa[mt], bb[i], po[i][mt]);
        }
        #pragma unroll
        for (int i = 0; i < 2; ++i) {
            int o = (wv * 2 + i) * 16 + ln;
            float pbv = proj_b[o];
            #pragma unroll
            for (int mt = 0; mt < 4; ++mt)
                #pragma unroll
                for (int r = 0; r < 4; ++r) {
                    int m = mt * 16 + g * 4 + r;
                    if (m < 49)
                        out[((size_t)b * 49 + m) * 192 + o] = po[i][mt][r] + pbv;
                }
        }
    }
}

extern "C" void kernel_launch(void* const* d_in, const int* in_sizes, int n_in,
                              void* d_out, int out_size, void* d_ws, size_t ws_size,
                              hipStream_t stream) {
    const float* x        = (const float*)d_in[0];
    const float* mask     = (const float*)d_in[1];
    const float* qkv_w    = (const float*)d_in[2];
    const float* qkv_b    = (const float*)d_in[3];
    const float* proj_w   = (const float*)d_in[4];
    const float* proj_b   = (const float*)d_in[5];
    const float* bias_tab = (const float*)d_in[6];
    const int*   rel_idx  = (const int*)d_in[7];

    __bf16* wqkv  = (__bf16*)d_ws;
    __bf16* wproj = wqkv + NWQKV;
    float*  biasf = (float*)((char*)d_ws + 294912);
    float*  maskf = (float*)((char*)d_ws + 393216);

    const int total = NWQKV + NWPROJ + NBIAS + NMASK;   // 434176
    prep_kernel<<<(total + 255) / 256, 256, 0, stream>>>(
        qkv_w, proj_w, bias_tab, rel_idx, mask, wqkv, wproj, biasf, maskf);

    win_attn_kernel<<<4096, 384, 0, stream>>>(
        x, qkv_b, proj_b, wqkv, wproj, biasf, maskf, (float*)d_out);
}